// Round 8
// baseline (190.341 us; speedup 1.0000x reference)
//
#include <hip/hip_runtime.h>
#include <hip/hip_bf16.h>
#include <cstdint>
#include <cstddef>

#define DEV static __device__ __forceinline__

typedef float f32x4 __attribute__((ext_vector_type(4)));
typedef float f32x2 __attribute__((ext_vector_type(2)));
typedef __bf16 bf16x8 __attribute__((ext_vector_type(8)));
typedef unsigned int u32x4 __attribute__((ext_vector_type(4)));
typedef unsigned int u32x2 __attribute__((ext_vector_type(2)));
typedef unsigned short us4v __attribute__((ext_vector_type(4)));

static constexpr int BATCH  = 4;
static constexpr int SEQ    = 4096;
static constexpr int DMODEL = 1024;
static constexpr int DHEAD  = 64;

// ws layout (bytes):
//   WTf bf16 [32 ktile][12 frag][64 lane][8]  @ 0        (393216)
//   Q   bf16 [B][S][64] (pre-scaled)          @ 393216   (2097152)
//   K   bf16 [B][S][64]                       @ 2490368  (2097152)
//   VT  bf16 [B][64][S]                       @ 4587520  (2097152)
static constexpr size_t WT_OFF = 0;
static constexpr size_t Q_OFF  = 393216;
static constexpr size_t K_OFF  = Q_OFF + 2097152;
static constexpr size_t VT_OFF = K_OFF + 2097152;

DEV unsigned short f2bf_bits(float f) {
    union { float f; unsigned u; } v; v.f = f;
    unsigned r = (v.u + 0x7fffu + ((v.u >> 16) & 1u)) >> 16;
    return (unsigned short)r;
}
DEV bf16x8 load_bf16x8(const unsigned short* p) {
    union { u32x4 u; bf16x8 b; } t;
    t.u = *(const u32x4*)p;
    return t.b;
}
DEV unsigned cvt_pk_bf16(float lo, float hi) {
    unsigned r;
    asm("v_cvt_pk_bf16_f32 %0, %1, %2" : "=v"(r) : "v"(lo), "v"(hi));
    return r;
}
// K=16 bf16 MFMA: A = P[q=lr][k=4*lg+e] (2 VGPR), B = V[k][d-col] (2 VGPR)
DEV f32x4 mfma_16x16x16_bf16(u32x2 a, u32x2 b, f32x4 c) {
    asm("v_mfma_f32_16x16x16_bf16 %0, %1, %2, %0" : "+v"(c) : "v"(a), "v"(b));
    return c;
}
// async global->LDS, 16B per lane; lds dest = wave-uniform base + lane*16
DEV void gl_lds16(const void* g, void* l) {
    __builtin_amdgcn_global_load_lds(
        (const __attribute__((address_space(1))) unsigned int*)g,
        (__attribute__((address_space(3))) unsigned int*)l, 16, 0, 0);
}

// ---------------- kernel 0: W fp32 -> WTf (fragment-linear bf16) ----------------
// WTf[kt][f][lane][e] = W_m[kt*32 + (lane>>4)*8 + e][ (f*16 + (lane&15)) & 63 ],
// m = (f*16 + (lane&15)) >> 6.  24576 threads x 8 elems.
__global__ __launch_bounds__(256) void wtrans_kernel(
        const float* __restrict__ Wq, const float* __restrict__ Wk,
        const float* __restrict__ Wv, unsigned short* __restrict__ WTf) {
    int idx = blockIdx.x * 256 + threadIdx.x;     // 0..24575
    int kt = idx / 768;
    int rem = idx - kt * 768;
    int f = rem >> 6, lane = rem & 63;
    int c = f * 16 + (lane & 15);
    int m = c >> 6, d = c & 63;
    int k0 = kt * 32 + (lane >> 4) * 8;
    const float* W = (m == 0) ? Wq : ((m == 1) ? Wk : Wv);
    unsigned short v[8];
#pragma unroll
    for (int e = 0; e < 8; ++e) v[e] = f2bf_bits(W[(size_t)(k0 + e) * DHEAD + d]);
    u32x4 o;
#pragma unroll
    for (int j = 0; j < 4; ++j) o[j] = (unsigned)v[2 * j] | ((unsigned)v[2 * j + 1] << 16);
    *(u32x4*)&WTf[(size_t)idx * 8] = o;
}

// ---------------- kernel 1: fused QKV projection ----------------
// grid 1024 x 256 thr (4 waves). Block = 16 rows x 192 cols; wave w owns
// frags 3w..3w+2 (48 cols) and self-stages them (no cross-wave wt dep).
// One barrier per k-step; x double-buffered in LDS.
__global__ __launch_bounds__(256, 4) void proj_kernel(
        const float* __restrict__ x, const unsigned short* __restrict__ WTf,
        unsigned short* __restrict__ Qs, unsigned short* __restrict__ Kd,
        unsigned short* __restrict__ VT) {
    __shared__ unsigned short xb[2][16][36];      // 2.3 KiB
    __shared__ unsigned short wt[2][6144];        // 24 KiB, frag-linear
    const int tid = threadIdx.x;
    const int w = tid >> 6, lane = tid & 63;
    const int lr = lane & 15, lg = lane >> 4;
    const int rowbase = blockIdx.x * 16;
    const int xrow = tid >> 4, xcp = tid & 15;    // x loader: row, col-pair

    const float* xsrc = x + (size_t)(rowbase + xrow) * DMODEL + xcp * 2;

    // prologue: stage wt(0), write xb(0), prefetch x(1)
#pragma unroll
    for (int f = 0; f < 3; ++f)
        gl_lds16(WTf + (size_t)(3 * w + f) * 512 + lane * 8, &wt[0][(3 * w + f) * 512]);
    f32x2 xcur = *(const f32x2*)xsrc;             // x(0); its wait drains wt(0)
    *(unsigned*)&xb[0][xrow][xcp * 2] = cvt_pk_bf16(xcur[0], xcur[1]);
    f32x2 xnext = *(const f32x2*)(xsrc + 32);     // x(1)

    f32x4 acc[3];
#pragma unroll
    for (int f = 0; f < 3; ++f) acc[f] = (f32x4){0.f, 0.f, 0.f, 0.f};
    __syncthreads();

    for (int k = 0; k < 32; ++k) {
        const int buf = k & 1;
        if (k < 31) {
            // write x(k+1) into other buf (waits x(k+1) -> drains wt(k))
            *(unsigned*)&xb[buf ^ 1][xrow][xcp * 2] = cvt_pk_bf16(xnext[0], xnext[1]);
#pragma unroll
            for (int f = 0; f < 3; ++f)           // self-stage wt(k+1)
                gl_lds16(WTf + ((size_t)(k + 1) * 12 + 3 * w + f) * 512 + lane * 8,
                         &wt[buf ^ 1][(3 * w + f) * 512]);
            if (k < 30) xnext = *(const f32x2*)(xsrc + (k + 2) * 32);
            asm volatile("s_waitcnt vmcnt(4)" ::: "memory");
        } else {
            asm volatile("s_waitcnt vmcnt(0)" ::: "memory");
        }

        bf16x8 af = load_bf16x8(&xb[buf][lr][lg * 8]);
#pragma unroll
        for (int f = 0; f < 3; ++f) {
            bf16x8 bf = load_bf16x8(&wt[buf][(3 * w + f) * 512 + lane * 8]);
            acc[f] = __builtin_amdgcn_mfma_f32_16x16x32_bf16(af, bf, acc[f], 0, 0, 0);
        }
        __syncthreads();
    }

    // epilogue: cols c = (3w+f)*16 + lr -> (m = c>>6, d = c&63)
    const float QSCALE = 0.18033688011112042f;    // 2^-3 * log2(e) folded for exp2
    const int b = rowbase >> 12;
    const int srow0 = (rowbase & 4095) + lg * 4;
#pragma unroll
    for (int f = 0; f < 3; ++f) {
        int c = (3 * w + f) * 16 + lr;
        int m = c >> 6, d = c & 63;
        if (m == 2) {
            us4v vv;
#pragma unroll
            for (int e = 0; e < 4; ++e) vv[e] = f2bf_bits(acc[f][e]);
            *(us4v*)&VT[((size_t)b * DHEAD + d) * SEQ + srow0] = vv;
        } else {
#pragma unroll
            for (int e = 0; e < 4; ++e) {
                size_t r = (size_t)rowbase + lg * 4 + e;
                if (m == 0) Qs[r * DHEAD + d] = f2bf_bits(acc[f][e] * QSCALE);
                else        Kd[r * DHEAD + d] = f2bf_bits(acc[f][e]);
            }
        }
    }
}

// ---------------- kernel 2: causal flash attention ----------------
// grid 1024 x 256 thr (4 waves). Block = one 16-row q-group; one shared
// 64-key K/V tile per step (double-buffered, 32 KiB); wave w owns keys
// [16w,16w+16) of every tile. P stays in registers (K=16 PV MFMA).
__global__ __launch_bounds__(256, 4) void attn_kernel(
        const unsigned short* __restrict__ Qs, const unsigned short* __restrict__ Kd,
        const unsigned short* __restrict__ VT, float* __restrict__ out) {
    __shared__ __align__(16) unsigned char smem[2][16384];  // [buf][K 8K | V 8K]
    const int tid = threadIdx.x;
    const int w = tid >> 6, lane = tid & 63;
    const int lr = lane & 15, lg = lane >> 4;

    const int b = blockIdx.x & 3;
    const int g = 255 - (blockIdx.x >> 2);        // longest q-groups first
    const int qbase = g * 16;
    const int nt = (qbase + 16 + 63) >> 6;        // 64-key tiles

    const unsigned short* Qb = Qs + (size_t)b * SEQ * DHEAD;
    const unsigned short* Kb = Kd + (size_t)b * SEQ * DHEAD;
    const unsigned short* Vb = VT + (size_t)b * DHEAD * SEQ;

    const bf16x8 qf0 = load_bf16x8(Qb + (size_t)(qbase + lr) * DHEAD + lg * 8);
    const bf16x8 qf1 = load_bf16x8(Qb + (size_t)(qbase + lr) * DHEAD + 32 + lg * 8);

    f32x4 o[4];
#pragma unroll
    for (int t = 0; t < 4; ++t) o[t] = (f32x4){0.f, 0.f, 0.f, 0.f};
    float m = -1e30f, l = 0.f;

    // coalesced stage of one 64-key tile (K 8K + V 8K), 16 chunks of 1 KiB
    const int sub = lane >> 3;                    // 0..7
    const int swz = (lane & 7) ^ sub;
    auto STAGE = [&](int s, int buf) {
        const int kv0 = s << 6;
#pragma unroll
        for (int c = 0; c < 4; ++c) {
            int ch = c * 4 + w;                   // 0..15, uniform per (c,w)
            unsigned char* dst = &smem[buf][ch * 1024];
            const unsigned short* src;
            if (ch < 8) {                         // K rows 8ch+sub
                int row = ch * 8 + sub;
                src = Kb + (size_t)(kv0 + row) * DHEAD + swz * 8;
            } else {                              // V rows d = 8(ch-8)+sub
                int d = (ch - 8) * 8 + sub;
                src = Vb + (size_t)d * SEQ + kv0 + swz * 8;
            }
            gl_lds16(src, dst);
        }
    };

    STAGE(0, 0);
    for (int s = 0; s < nt; ++s) {
        const int buf = s & 1;
        __syncthreads();                          // compute(s-1) done: safe overwrite
        if (s + 1 < nt) {
            STAGE(s + 1, buf ^ 1);
            asm volatile("s_waitcnt vmcnt(4)" ::: "memory");   // tile s landed
        } else {
            asm volatile("s_waitcnt vmcnt(0)" ::: "memory");
        }
        __syncthreads();                          // staged data visible to all

        const int kv0 = s << 6;
        const int kk = kv0 + 16 * w;              // this wave's 16-key slice
        if (kk <= qbase + 15) {
            const unsigned char* Kt = smem[buf];
            const unsigned char* Vt = smem[buf] + 8192;

            // QK^T (swapped): A = K rows kk+lr, B = Q -> S^T[k=kk+4lg+e][q=qbase+lr]
            bf16x8 kf0 = load_bf16x8((const unsigned short*)(
                Kt + (16 * w + lr) * 128 + ((lg ^ (lr & 7)) * 16)));
            bf16x8 kf1 = load_bf16x8((const unsigned short*)(
                Kt + (16 * w + lr) * 128 + (((4 + lg) ^ (lr & 7)) * 16)));
            f32x4 sf = (f32x4){0.f, 0.f, 0.f, 0.f};
            sf = __builtin_amdgcn_mfma_f32_16x16x32_bf16(kf0, qf0, sf, 0, 0, 0);
            sf = __builtin_amdgcn_mfma_f32_16x16x32_bf16(kf1, qf1, sf, 0, 0, 0);

            if (kk + 15 > qbase) {                // causal mask (wave-uniform branch)
#pragma unroll
                for (int e = 0; e < 4; ++e)
                    if (kk + 4 * lg + e > qbase + lr) sf[e] = -1e30f;
            }

            // slice max: 3 in-lane + 2 shfl (over lg)
            float mb = fmaxf(fmaxf(sf[0], sf[1]), fmaxf(sf[2], sf[3]));
            mb = fmaxf(mb, __shfl_xor(mb, 16));
            mb = fmaxf(mb, __shfl_xor(mb, 32));

            if (__any(mb > m)) {                  // defer-max
                float mn = fmaxf(m, mb);
                float sc = exp2f(m - mn);
                m = mn;
                l *= sc;
#pragma unroll
                for (int e = 0; e < 4; ++e) {
                    float sce = __shfl(sc, (lane & 48) | (lg * 4 + e));
#pragma unroll
                    for (int t = 0; t < 4; ++t) o[t][e] *= sce;
                }
            }

            float ssum = 0.f;
#pragma unroll
            for (int e = 0; e < 4; ++e) {
                float pv = exp2f(sf[e] - m);
                sf[e] = pv;
                ssum += pv;
            }
            ssum += __shfl_xor(ssum, 16);
            ssum += __shfl_xor(ssum, 32);
            l += ssum;

            // P in registers: A-frag[q=lr][k=4lg+e] == held S^T layout
            u32x2 pa;
            pa[0] = cvt_pk_bf16(sf[0], sf[1]);
            pa[1] = cvt_pk_bf16(sf[2], sf[3]);

#pragma unroll
            for (int t = 0; t < 4; ++t) {
                // B-frag: V[kk+4lg+e][16t+lr] via 8B read from swizzled V tile
                u32x2 vf = *(const u32x2*)(Vt + (16 * t + lr) * 128 +
                        (((2 * w + (lg >> 1)) ^ (lr & 7)) * 16) + (lg & 1) * 8);
                o[t] = mfma_16x16x16_bf16(pa, vf, o[t]);
            }
        }
    }

    // merge the 4 waves' partials (m, l, o) via LDS overlaid on tile area
    __syncthreads();
    float* olds = (float*)smem;                   // 3 x 1088 floats
    float* mlds = olds + 3 * 1088;
    float* llds = mlds + 48;
    if (w != 0) {
#pragma unroll
        for (int t = 0; t < 4; ++t)
#pragma unroll
            for (int e = 0; e < 4; ++e)
                olds[(w - 1) * 1088 + (lg * 4 + e) * 68 + t * 16 + lr] = o[t][e];
        if (lg == 0) { mlds[(w - 1) * 16 + lr] = m; llds[(w - 1) * 16 + lr] = l; }
    }
    __syncthreads();
    if (w == 0) {
        float mw[3], lw[3];
        float ms = m;
#pragma unroll
        for (int j = 0; j < 3; ++j) {
            mw[j] = mlds[j * 16 + lr]; lw[j] = llds[j * 16 + lr];
            ms = fmaxf(ms, mw[j]);
        }
        float a0 = exp2f(m - ms);
        float aw[3];
        float L = a0 * l;
#pragma unroll
        for (int j = 0; j < 3; ++j) { aw[j] = exp2f(mw[j] - ms); L += aw[j] * lw[j]; }
        float inv = 1.f / L;
        a0 *= inv;
#pragma unroll
        for (int j = 0; j < 3; ++j) aw[j] *= inv;

        float* ob = out + ((size_t)b * SEQ + qbase) * DHEAD;
#pragma unroll
        for (int e = 0; e < 4; ++e) {
            int src = (lane & 48) | (lg * 4 + e);
            float A0 = __shfl(a0, src);
            float A1 = __shfl(aw[0], src);
            float A2 = __shfl(aw[1], src);
            float A3 = __shfl(aw[2], src);
#pragma unroll
            for (int t = 0; t < 4; ++t) {
                float v = o[t][e] * A0
                        + olds[0 * 1088 + (lg * 4 + e) * 68 + t * 16 + lr] * A1
                        + olds[1 * 1088 + (lg * 4 + e) * 68 + t * 16 + lr] * A2
                        + olds[2 * 1088 + (lg * 4 + e) * 68 + t * 16 + lr] * A3;
                ob[(size_t)(lg * 4 + e) * DHEAD + t * 16 + lr] = v;
            }
        }
    }
}

extern "C" void kernel_launch(void* const* d_in, const int* in_sizes, int n_in,
                              void* d_out, int out_size, void* d_ws, size_t ws_size,
                              hipStream_t stream) {
    const float* x  = (const float*)d_in[0];
    const float* Wq = (const float*)d_in[1];
    const float* Wk = (const float*)d_in[2];
    const float* Wv = (const float*)d_in[3];
    float* out = (float*)d_out;

    char* ws = (char*)d_ws;
    unsigned short* WTf = (unsigned short*)(ws + WT_OFF);
    unsigned short* Q   = (unsigned short*)(ws + Q_OFF);
    unsigned short* K   = (unsigned short*)(ws + K_OFF);
    unsigned short* VT  = (unsigned short*)(ws + VT_OFF);

    hipLaunchKernelGGL(wtrans_kernel, dim3(96),   dim3(256), 0, stream, Wq, Wk, Wv, WTf);
    hipLaunchKernelGGL(proj_kernel,   dim3(1024), dim3(256), 0, stream, x, WTf, Q, K, VT);
    hipLaunchKernelGGL(attn_kernel,   dim3(1024), dim3(256), 0, stream, Q, K, VT, out);
}